// Round 1
// baseline (208.935 us; speedup 1.0000x reference)
//
#include <hip/hip_runtime.h>
#include <stdint.h>

#define B_ 16
#define N_ 256
#define T_ 128
#define K_ 128
#define H_ 16
#define G_ 1024                 // interpolation grid points
#define NELEM (B_*N_*N_)        // 1048576

// ---- order-preserving float<->uint encoding for atomic min/max ----
__device__ __forceinline__ uint32_t enc_f32(float f) {
    uint32_t u = __float_as_uint(f);
    return (u & 0x80000000u) ? ~u : (u | 0x80000000u);
}
__device__ __forceinline__ float dec_f32(uint32_t u) {
    uint32_t b = (u & 0x80000000u) ? (u ^ 0x80000000u) : ~u;
    return __uint_as_float(b);
}
__device__ __forceinline__ float fix_nonfinite(float v) {
    // nan_to_num(nan=0, posinf=0, neginf=0)
    uint32_t u = __float_as_uint(v);
    return ((u & 0x7F800000u) == 0x7F800000u) ? 0.0f : v;
}

// ---- kernel 0: init the min/max cells (ws is poisoned 0xAA each run) ----
__global__ void k_init(uint32_t* mm) {
    mm[0] = 0xFFFFFFFFu;  // running min (encoded)
    mm[1] = 0x00000000u;  // running max (encoded)
}

// ---- kernel 1: exact min/max of s = gamma*d + beta ----
__global__ __launch_bounds__(256) void k_minmax(
        const float* __restrict__ d, const int* __restrict__ tokens,
        const float* __restrict__ gamma_t, const float* __restrict__ beta_t,
        uint32_t* __restrict__ mm) {
    uint32_t lmin = 0xFFFFFFFFu, lmax = 0u;
    int stride = gridDim.x * blockDim.x;
    for (int e = blockIdx.x * blockDim.x + threadIdx.x; e < NELEM; e += stride) {
        int b = e >> 16, n = (e >> 8) & 255, m = e & 255;
        float dv = fix_nonfinite(d[e]);
        int ti = tokens[(b << 8) + n];
        int tj = tokens[(b << 8) + m];
        float s = fmaf(gamma_t[ti * T_ + tj], dv, beta_t[ti * T_ + tj]);
        uint32_t u = enc_f32(s);
        lmin = min(lmin, u);
        lmax = max(lmax, u);
    }
    // wave64 butterfly reduce
    #pragma unroll
    for (int off = 32; off > 0; off >>= 1) {
        lmin = min(lmin, (uint32_t)__shfl_down((unsigned int)lmin, off, 64));
        lmax = max(lmax, (uint32_t)__shfl_down((unsigned int)lmax, off, 64));
    }
    if ((threadIdx.x & 63) == 0) {
        atomicMin(&mm[0], lmin);
        atomicMax(&mm[1], lmax);
    }
}

// ---- kernel 2: tabulate f(s) = W2^T relu(W1^T psi(s) + b1) + b2 on a grid ----
__global__ __launch_bounds__(128) void k_table(
        const uint32_t* __restrict__ mm,
        const float* __restrict__ mu, const float* __restrict__ log_sigma,
        const float* __restrict__ W1, const float* __restrict__ b1,
        const float* __restrict__ W2, const float* __restrict__ b2,
        float* __restrict__ table) {
    __shared__ float psi[K_];
    __shared__ float hv[K_];
    float smin = dec_f32(mm[0]);
    float smax = dec_f32(mm[1]);
    float s = smin + (smax - smin) * ((float)blockIdx.x / (float)(G_ - 1));
    int t = threadIdx.x;
    // psi_k(s)
    float ls  = log_sigma[t];
    float sig = fmaxf(ls, 0.0f) + log1pf(expf(-fabsf(ls))) + 1e-6f; // softplus + 1e-6
    float x   = (s - mu[t]) / sig;
    psi[t] = expf(-0.5f * x * x) / (2.5066282746310002f * sig);  // /(sqrt(2pi)*sig)
    __syncthreads();
    // h_j = relu(psi . W1[:,j] + b1[j])
    float acc = b1[t];
    #pragma unroll 8
    for (int k = 0; k < K_; k++) acc = fmaf(psi[k], W1[k * K_ + t], acc);
    hv[t] = fmaxf(acc, 0.0f);
    __syncthreads();
    // phi_h = h . W2[:,h] + b2[h]
    if (t < H_) {
        float a2 = b2[t];
        #pragma unroll 8
        for (int j = 0; j < K_; j++) a2 = fmaf(hv[j], W2[j * H_ + t], a2);
        table[blockIdx.x * H_ + t] = a2;
    }
}

// ---- kernel 3: main — interpolate table per element, write (B,H,N,N) ----
__global__ __launch_bounds__(512) void k_main(
        const float* __restrict__ d, const int* __restrict__ tokens,
        const float* __restrict__ gamma_t, const float* __restrict__ beta_t,
        const uint32_t* __restrict__ mm, const float* __restrict__ table,
        float* __restrict__ out) {
    __shared__ float4 tab[G_ * 4];   // 64 KB: row i -> tab[4i..4i+3]
    const float4* tg = (const float4*)table;
    for (int i = threadIdx.x; i < G_ * 4; i += blockDim.x) tab[i] = tg[i];

    float smin  = dec_f32(mm[0]);
    float range = dec_f32(mm[1]) - smin;
    float invd  = (range > 1e-30f) ? (float)(G_ - 1) / range : 0.0f;
    __syncthreads();

    int stride = gridDim.x * blockDim.x;
    for (int e = blockIdx.x * blockDim.x + threadIdx.x; e < NELEM; e += stride) {
        int b = e >> 16, n = (e >> 8) & 255, m = e & 255;
        float dv = fix_nonfinite(d[e]);
        int ti = tokens[(b << 8) + n];
        int tj = tokens[(b << 8) + m];
        float s = fmaf(gamma_t[ti * T_ + tj], dv, beta_t[ti * T_ + tj]);

        float tpos = (s - smin) * invd;
        tpos = fminf(fmaxf(tpos, 0.0f), (float)(G_ - 1));
        int i0 = (int)tpos;
        if (i0 > G_ - 2) i0 = G_ - 2;
        float fr = tpos - (float)i0;

        float4 a0 = tab[i0 * 4 + 0], a1 = tab[i0 * 4 + 1],
               a2 = tab[i0 * 4 + 2], a3 = tab[i0 * 4 + 3];
        float4 c0 = tab[i0 * 4 + 4], c1 = tab[i0 * 4 + 5],
               c2 = tab[i0 * 4 + 6], c3 = tab[i0 * 4 + 7];

        float o[16];
        o[ 0] = fmaf(fr, c0.x - a0.x, a0.x); o[ 1] = fmaf(fr, c0.y - a0.y, a0.y);
        o[ 2] = fmaf(fr, c0.z - a0.z, a0.z); o[ 3] = fmaf(fr, c0.w - a0.w, a0.w);
        o[ 4] = fmaf(fr, c1.x - a1.x, a1.x); o[ 5] = fmaf(fr, c1.y - a1.y, a1.y);
        o[ 6] = fmaf(fr, c1.z - a1.z, a1.z); o[ 7] = fmaf(fr, c1.w - a1.w, a1.w);
        o[ 8] = fmaf(fr, c2.x - a2.x, a2.x); o[ 9] = fmaf(fr, c2.y - a2.y, a2.y);
        o[10] = fmaf(fr, c2.z - a2.z, a2.z); o[11] = fmaf(fr, c2.w - a2.w, a2.w);
        o[12] = fmaf(fr, c3.x - a3.x, a3.x); o[13] = fmaf(fr, c3.y - a3.y, a3.y);
        o[14] = fmaf(fr, c3.z - a3.z, a3.z); o[15] = fmaf(fr, c3.w - a3.w, a3.w);

        // out[b][h][n][m]; base = b*H*N*N + n*N + m, stride per h = N*N
        size_t base = ((size_t)(uint32_t)(e & 0xFFFF0000) << 4) | (uint32_t)(e & 0xFFFF);
        #pragma unroll
        for (int hh = 0; hh < 16; hh++)
            out[base + (size_t)hh * (N_ * N_)] = o[hh];
    }
}

extern "C" void kernel_launch(void* const* d_in, const int* in_sizes, int n_in,
                              void* d_out, int out_size, void* d_ws, size_t ws_size,
                              hipStream_t stream) {
    const float* d_mat     = (const float*)d_in[0];
    const int*   tokens    = (const int*)  d_in[1];
    const float* mu        = (const float*)d_in[2];
    const float* log_sigma = (const float*)d_in[3];
    const float* W1        = (const float*)d_in[4];
    const float* b1        = (const float*)d_in[5];
    const float* W2        = (const float*)d_in[6];
    const float* b2        = (const float*)d_in[7];
    const float* gamma_t   = (const float*)d_in[8];
    const float* beta_t    = (const float*)d_in[9];
    float* out = (float*)d_out;

    uint32_t* mm   = (uint32_t*)d_ws;              // 2 cells min/max
    float*   table = (float*)d_ws + 16;            // 64B-aligned, G_*H_ floats (64 KB)

    k_init<<<1, 1, 0, stream>>>(mm);
    k_minmax<<<1024, 256, 0, stream>>>(d_mat, tokens, gamma_t, beta_t, mm);
    k_table<<<G_, 128, 0, stream>>>(mm, mu, log_sigma, W1, b1, W2, b2, table);
    k_main<<<1024, 512, 0, stream>>>(d_mat, tokens, gamma_t, beta_t, mm, table, out);
}

// Round 2
// 113.161 us; speedup vs baseline: 1.8464x; 1.8464x over previous
//
#include <hip/hip_runtime.h>
#include <stdint.h>

#define B_ 16
#define N_ 256
#define T_ 128
#define K_ 128
#define H_ 16
#define G_ 1024                 // interpolation grid points
#define NELEM (B_*N_*N_)        // 1048576
#define NF4   (NELEM/4)         // 262144 float4 elements of d

// ---- order-preserving float<->uint encoding for min/max reduction ----
__device__ __forceinline__ uint32_t enc_f32(float f) {
    uint32_t u = __float_as_uint(f);
    return (u & 0x80000000u) ? ~u : (u | 0x80000000u);
}
__device__ __forceinline__ float dec_f32(uint32_t u) {
    uint32_t b = (u & 0x80000000u) ? (u ^ 0x80000000u) : ~u;
    return __uint_as_float(b);
}
__device__ __forceinline__ float fix_nonfinite(float v) {
    // nan_to_num(nan=0, posinf=0, neginf=0)
    uint32_t u = __float_as_uint(v);
    return ((u & 0x7F800000u) == 0x7F800000u) ? 0.0f : v;
}

// ---- kernel 1: per-block min/max partials of s = gamma*d + beta (NO atomics) ----
__global__ __launch_bounds__(256) void k_partial(
        const float4* __restrict__ d4, const int* __restrict__ tokens,
        const float* __restrict__ gamma_t, const float* __restrict__ beta_t,
        uint32_t* __restrict__ pmin, uint32_t* __restrict__ pmax) {
    uint32_t lmin = 0xFFFFFFFFu, lmax = 0u;
    #pragma unroll
    for (int i = 0; i < 4; i++) {
        int idx = blockIdx.x * 256 + threadIdx.x + i * 65536;   // float4 index
        int e0 = idx << 2;
        int b = e0 >> 16, n = (e0 >> 8) & 255, m0 = e0 & 255;
        float4 dv = d4[idx];
        int ti = tokens[(b << 8) + n];
        int4 tj = *(const int4*)&tokens[(b << 8) + m0];
        const float* grow = gamma_t + ti * T_;
        const float* brow = beta_t  + ti * T_;
        float s0 = fmaf(grow[tj.x], fix_nonfinite(dv.x), brow[tj.x]);
        float s1 = fmaf(grow[tj.y], fix_nonfinite(dv.y), brow[tj.y]);
        float s2 = fmaf(grow[tj.z], fix_nonfinite(dv.z), brow[tj.z]);
        float s3 = fmaf(grow[tj.w], fix_nonfinite(dv.w), brow[tj.w]);
        uint32_t u0 = enc_f32(s0), u1 = enc_f32(s1);
        uint32_t u2 = enc_f32(s2), u3 = enc_f32(s3);
        lmin = min(min(lmin, u0), min(u1, min(u2, u3)));
        lmax = max(max(lmax, u0), max(u1, max(u2, u3)));
    }
    #pragma unroll
    for (int off = 32; off > 0; off >>= 1) {
        lmin = min(lmin, (uint32_t)__shfl_down((unsigned int)lmin, off, 64));
        lmax = max(lmax, (uint32_t)__shfl_down((unsigned int)lmax, off, 64));
    }
    __shared__ uint32_t wmin[4], wmax[4];
    int wave = threadIdx.x >> 6;
    if ((threadIdx.x & 63) == 0) { wmin[wave] = lmin; wmax[wave] = lmax; }
    __syncthreads();
    if (threadIdx.x == 0) {
        uint32_t bm = min(min(wmin[0], wmin[1]), min(wmin[2], wmin[3]));
        uint32_t bM = max(max(wmax[0], wmax[1]), max(wmax[2], wmax[3]));
        pmin[blockIdx.x] = bm;
        pmax[blockIdx.x] = bM;
    }
}

// ---- kernel 2: fold 256 partial pairs -> mm[0..1] ----
__global__ __launch_bounds__(256) void k_reduce(
        const uint32_t* __restrict__ pmin, const uint32_t* __restrict__ pmax,
        uint32_t* __restrict__ mm) {
    uint32_t lmin = pmin[threadIdx.x];
    uint32_t lmax = pmax[threadIdx.x];
    #pragma unroll
    for (int off = 32; off > 0; off >>= 1) {
        lmin = min(lmin, (uint32_t)__shfl_down((unsigned int)lmin, off, 64));
        lmax = max(lmax, (uint32_t)__shfl_down((unsigned int)lmax, off, 64));
    }
    __shared__ uint32_t wmin[4], wmax[4];
    int wave = threadIdx.x >> 6;
    if ((threadIdx.x & 63) == 0) { wmin[wave] = lmin; wmax[wave] = lmax; }
    __syncthreads();
    if (threadIdx.x == 0) {
        mm[0] = min(min(wmin[0], wmin[1]), min(wmin[2], wmin[3]));
        mm[1] = max(max(wmax[0], wmax[1]), max(wmax[2], wmax[3]));
    }
}

// ---- kernel 3: tabulate f(s) = W2^T relu(W1^T psi(s) + b1) + b2 on a grid ----
__global__ __launch_bounds__(128) void k_table(
        const uint32_t* __restrict__ mm,
        const float* __restrict__ mu, const float* __restrict__ log_sigma,
        const float* __restrict__ W1, const float* __restrict__ b1,
        const float* __restrict__ W2, const float* __restrict__ b2,
        float* __restrict__ table) {
    __shared__ float psi[K_];
    __shared__ float hv[K_];
    float smin = dec_f32(mm[0]);
    float smax = dec_f32(mm[1]);
    float s = smin + (smax - smin) * ((float)blockIdx.x / (float)(G_ - 1));
    int t = threadIdx.x;
    float ls  = log_sigma[t];
    float sig = fmaxf(ls, 0.0f) + log1pf(expf(-fabsf(ls))) + 1e-6f; // softplus + 1e-6
    float x   = (s - mu[t]) / sig;
    psi[t] = expf(-0.5f * x * x) / (2.5066282746310002f * sig);  // /(sqrt(2pi)*sig)
    __syncthreads();
    float acc = b1[t];
    #pragma unroll 8
    for (int k = 0; k < K_; k++) acc = fmaf(psi[k], W1[k * K_ + t], acc);
    hv[t] = fmaxf(acc, 0.0f);
    __syncthreads();
    if (t < H_) {
        float a2 = b2[t];
        #pragma unroll 8
        for (int j = 0; j < K_; j++) a2 = fmaf(hv[j], W2[j * H_ + t], a2);
        table[blockIdx.x * H_ + t] = a2;
    }
}

// ---- kernel 4: main — 4 consecutive m per thread, float4 I/O throughout ----
__global__ __launch_bounds__(512) void k_main(
        const float4* __restrict__ d4, const int* __restrict__ tokens,
        const float* __restrict__ gamma_t, const float* __restrict__ beta_t,
        const uint32_t* __restrict__ mm, const float4* __restrict__ tg,
        float* __restrict__ out) {
    __shared__ float4 tab[G_ * 4];   // 64 KB: row i -> tab[4i..4i+3]
    #pragma unroll
    for (int i = 0; i < 8; i++) tab[threadIdx.x + i * 512] = tg[threadIdx.x + i * 512];

    float smin  = dec_f32(mm[0]);
    float range = dec_f32(mm[1]) - smin;
    float invd  = (range > 1e-30f) ? (float)(G_ - 1) / range : 0.0f;
    __syncthreads();

    int idx = blockIdx.x * 512 + threadIdx.x;     // float4 index, one per thread
    int e0 = idx << 2;
    int b = e0 >> 16, n = (e0 >> 8) & 255, m0 = e0 & 255;
    float4 dv = d4[idx];
    int ti = tokens[(b << 8) + n];
    int4 tj = *(const int4*)&tokens[(b << 8) + m0];
    const float* grow = gamma_t + ti * T_;
    const float* brow = beta_t  + ti * T_;

    float s[4];
    s[0] = fmaf(grow[tj.x], fix_nonfinite(dv.x), brow[tj.x]);
    s[1] = fmaf(grow[tj.y], fix_nonfinite(dv.y), brow[tj.y]);
    s[2] = fmaf(grow[tj.z], fix_nonfinite(dv.z), brow[tj.z]);
    s[3] = fmaf(grow[tj.w], fix_nonfinite(dv.w), brow[tj.w]);

    int   i0[4];
    float fr[4];
    #pragma unroll
    for (int c = 0; c < 4; c++) {
        float tpos = (s[c] - smin) * invd;
        tpos = fminf(fmaxf(tpos, 0.0f), (float)(G_ - 1));
        int i = (int)tpos;
        if (i > G_ - 2) i = G_ - 2;
        i0[c] = i;
        fr[c] = tpos - (float)i;
    }

    // out[b][h][n][m0..m0+3]; base = b*H*N*N + n*N + m0
    size_t base = ((size_t)b << 20) | (uint32_t)(e0 & 0xFFFF);

    #pragma unroll
    for (int hq = 0; hq < 4; hq++) {             // h-quad: h = 4*hq .. 4*hq+3
        float4 P[4];
        #pragma unroll
        for (int c = 0; c < 4; c++) {
            float4 A  = tab[i0[c] * 4 + hq];
            float4 Bv = tab[i0[c] * 4 + 4 + hq];
            P[c].x = fmaf(fr[c], Bv.x - A.x, A.x);
            P[c].y = fmaf(fr[c], Bv.y - A.y, A.y);
            P[c].z = fmaf(fr[c], Bv.z - A.z, A.z);
            P[c].w = fmaf(fr[c], Bv.w - A.w, A.w);
        }
        float4 o0 = make_float4(P[0].x, P[1].x, P[2].x, P[3].x);
        float4 o1 = make_float4(P[0].y, P[1].y, P[2].y, P[3].y);
        float4 o2 = make_float4(P[0].z, P[1].z, P[2].z, P[3].z);
        float4 o3 = make_float4(P[0].w, P[1].w, P[2].w, P[3].w);
        *(float4*)&out[base + (size_t)(hq * 4 + 0) * (N_ * N_)] = o0;
        *(float4*)&out[base + (size_t)(hq * 4 + 1) * (N_ * N_)] = o1;
        *(float4*)&out[base + (size_t)(hq * 4 + 2) * (N_ * N_)] = o2;
        *(float4*)&out[base + (size_t)(hq * 4 + 3) * (N_ * N_)] = o3;
    }
}

extern "C" void kernel_launch(void* const* d_in, const int* in_sizes, int n_in,
                              void* d_out, int out_size, void* d_ws, size_t ws_size,
                              hipStream_t stream) {
    const float* d_mat     = (const float*)d_in[0];
    const int*   tokens    = (const int*)  d_in[1];
    const float* mu        = (const float*)d_in[2];
    const float* log_sigma = (const float*)d_in[3];
    const float* W1        = (const float*)d_in[4];
    const float* b1        = (const float*)d_in[5];
    const float* W2        = (const float*)d_in[6];
    const float* b2        = (const float*)d_in[7];
    const float* gamma_t   = (const float*)d_in[8];
    const float* beta_t    = (const float*)d_in[9];
    float* out = (float*)d_out;

    uint32_t* mm    = (uint32_t*)d_ws;                  // 2 cells min/max (enc)
    uint32_t* pmin  = (uint32_t*)d_ws + 64;             // 256 partial mins
    uint32_t* pmax  = (uint32_t*)d_ws + 64 + 256;       // 256 partial maxs
    float*    table = (float*)d_ws + 1024;              // G_*H_ floats (64 KB), 16B-aligned

    k_partial<<<256, 256, 0, stream>>>((const float4*)d_mat, tokens, gamma_t, beta_t,
                                       pmin, pmax);
    k_reduce<<<1, 256, 0, stream>>>(pmin, pmax, mm);
    k_table<<<G_, 128, 0, stream>>>(mm, mu, log_sigma, W1, b1, W2, b2, table);
    k_main<<<512, 512, 0, stream>>>((const float4*)d_mat, tokens, gamma_t, beta_t,
                                    mm, (const float4*)table, out);
}

// Round 3
// 113.070 us; speedup vs baseline: 1.8478x; 1.0008x over previous
//
#include <hip/hip_runtime.h>
#include <stdint.h>

#define B_ 16
#define N_ 256
#define T_ 128
#define K_ 128
#define H_ 16
#define G_ 1024                 // interpolation grid points
#define NELEM (B_*N_*N_)        // 1048576

// ---- order-preserving float<->uint encoding for min/max reduction ----
__device__ __forceinline__ uint32_t enc_f32(float f) {
    uint32_t u = __float_as_uint(f);
    return (u & 0x80000000u) ? ~u : (u | 0x80000000u);
}
__device__ __forceinline__ float dec_f32(uint32_t u) {
    uint32_t b = (u & 0x80000000u) ? (u ^ 0x80000000u) : ~u;
    return __uint_as_float(b);
}
__device__ __forceinline__ float fix_nonfinite(float v) {
    // nan_to_num(nan=0, posinf=0, neginf=0)
    uint32_t u = __float_as_uint(v);
    return ((u & 0x7F800000u) == 0x7F800000u) ? 0.0f : v;
}

// ---- kernel 1: per-block min/max partials of s = gamma*d + beta (NO atomics) ----
__global__ __launch_bounds__(256) void k_partial(
        const float4* __restrict__ d4, const int* __restrict__ tokens,
        const float* __restrict__ gamma_t, const float* __restrict__ beta_t,
        uint32_t* __restrict__ pmin, uint32_t* __restrict__ pmax) {
    uint32_t lmin = 0xFFFFFFFFu, lmax = 0u;
    #pragma unroll
    for (int i = 0; i < 4; i++) {
        int idx = blockIdx.x * 256 + threadIdx.x + i * 65536;   // float4 index
        int e0 = idx << 2;
        int b = e0 >> 16, n = (e0 >> 8) & 255, m0 = e0 & 255;
        float4 dv = d4[idx];
        int ti = tokens[(b << 8) + n];
        int4 tj = *(const int4*)&tokens[(b << 8) + m0];
        const float* grow = gamma_t + ti * T_;
        const float* brow = beta_t  + ti * T_;
        float s0 = fmaf(grow[tj.x], fix_nonfinite(dv.x), brow[tj.x]);
        float s1 = fmaf(grow[tj.y], fix_nonfinite(dv.y), brow[tj.y]);
        float s2 = fmaf(grow[tj.z], fix_nonfinite(dv.z), brow[tj.z]);
        float s3 = fmaf(grow[tj.w], fix_nonfinite(dv.w), brow[tj.w]);
        uint32_t u0 = enc_f32(s0), u1 = enc_f32(s1);
        uint32_t u2 = enc_f32(s2), u3 = enc_f32(s3);
        lmin = min(min(lmin, u0), min(u1, min(u2, u3)));
        lmax = max(max(lmax, u0), max(u1, max(u2, u3)));
    }
    #pragma unroll
    for (int off = 32; off > 0; off >>= 1) {
        lmin = min(lmin, (uint32_t)__shfl_down((unsigned int)lmin, off, 64));
        lmax = max(lmax, (uint32_t)__shfl_down((unsigned int)lmax, off, 64));
    }
    __shared__ uint32_t wmin[4], wmax[4];
    int wave = threadIdx.x >> 6;
    if ((threadIdx.x & 63) == 0) { wmin[wave] = lmin; wmax[wave] = lmax; }
    __syncthreads();
    if (threadIdx.x == 0) {
        pmin[blockIdx.x] = min(min(wmin[0], wmin[1]), min(wmin[2], wmin[3]));
        pmax[blockIdx.x] = max(max(wmax[0], wmax[1]), max(wmax[2], wmax[3]));
    }
}

// ---- kernel 2: fused (reduce 256 partials) + tabulate f(s) on the grid ----
__global__ __launch_bounds__(128) void k_table(
        const uint32_t* __restrict__ pmin, const uint32_t* __restrict__ pmax,
        const float* __restrict__ mu, const float* __restrict__ log_sigma,
        const float* __restrict__ W1, const float* __restrict__ b1,
        const float* __restrict__ W2, const float* __restrict__ b2,
        float* __restrict__ table, float* __restrict__ mmf) {
    __shared__ float psi[K_];
    __shared__ float hv[K_];
    __shared__ uint32_t wmin[2], wmax[2];
    int t = threadIdx.x;

    // every block redundantly folds the 256 partial pairs (cheap, L2-hit)
    uint32_t lmin = min(pmin[t], pmin[t + 128]);
    uint32_t lmax = max(pmax[t], pmax[t + 128]);
    #pragma unroll
    for (int off = 32; off > 0; off >>= 1) {
        lmin = min(lmin, (uint32_t)__shfl_down((unsigned int)lmin, off, 64));
        lmax = max(lmax, (uint32_t)__shfl_down((unsigned int)lmax, off, 64));
    }
    if ((t & 63) == 0) { wmin[t >> 6] = lmin; wmax[t >> 6] = lmax; }
    __syncthreads();
    float smin = dec_f32(min(wmin[0], wmin[1]));
    float smax = dec_f32(max(wmax[0], wmax[1]));
    if (blockIdx.x == 0 && t == 0) { mmf[0] = smin; mmf[1] = smax; }

    float s = smin + (smax - smin) * ((float)blockIdx.x / (float)(G_ - 1));
    float ls  = log_sigma[t];
    float sig = fmaxf(ls, 0.0f) + log1pf(expf(-fabsf(ls))) + 1e-6f; // softplus + 1e-6
    float x   = (s - mu[t]) / sig;
    psi[t] = expf(-0.5f * x * x) / (2.5066282746310002f * sig);  // /(sqrt(2pi)*sig)
    __syncthreads();
    float acc = b1[t];
    #pragma unroll 8
    for (int k = 0; k < K_; k++) acc = fmaf(psi[k], W1[k * K_ + t], acc);
    hv[t] = fmaxf(acc, 0.0f);
    __syncthreads();
    if (t < H_) {
        float a2 = b2[t];
        #pragma unroll 8
        for (int j = 0; j < K_; j++) a2 = fmaf(hv[j], W2[j * H_ + t], a2);
        table[blockIdx.x * H_ + t] = a2;
    }
}

// ---- kernel 3: main — table + per-block gamma/beta rows in LDS, float4 I/O ----
__global__ __launch_bounds__(512) void k_main(
        const float4* __restrict__ d4, const int* __restrict__ tokens,
        const float* __restrict__ gamma_t, const float* __restrict__ beta_t,
        const float* __restrict__ mmf, const float4* __restrict__ tg,
        float* __restrict__ out) {
    __shared__ float4 tab[G_ * 4];      // 64 KB: grid row i -> tab[4i..4i+3]
    __shared__ float  grow_lds[8 * K_]; // 4 KB: gamma rows for this block's 8 n
    __shared__ float  brow_lds[8 * K_]; // 4 KB: beta rows
    int tid = threadIdx.x;

    #pragma unroll
    for (int i = 0; i < 8; i++) tab[tid + i * 512] = tg[tid + i * 512];

    int base_e = blockIdx.x * 2048;        // first element of this block
    int b  = base_e >> 16;                 // batch (uniform in block)
    int n0 = (base_e >> 8) & 255;          // first n-row (block spans 8 rows)
    if (tid < 256) {
        int r  = tid >> 5;                 // row 0..7
        int c4 = (tid & 31) << 2;          // col 0,4,...,124
        int ti = tokens[(b << 8) + n0 + r];
        *(float4*)&grow_lds[r * K_ + c4] = *(const float4*)&gamma_t[ti * T_ + c4];
    } else {
        int t2 = tid - 256;
        int r  = t2 >> 5;
        int c4 = (t2 & 31) << 2;
        int ti = tokens[(b << 8) + n0 + r];
        *(float4*)&brow_lds[r * K_ + c4] = *(const float4*)&beta_t[ti * T_ + c4];
    }

    float smin  = mmf[0];
    float range = mmf[1] - smin;
    float invd  = (range > 1e-30f) ? (float)(G_ - 1) / range : 0.0f;
    __syncthreads();

    int idx = blockIdx.x * 512 + tid;      // float4 index, one per thread
    int e0 = idx << 2;
    int w  = tid >> 6;                     // n-row within block (wave-uniform)
    int m0 = e0 & 255;
    float4 dv = d4[idx];
    int4 tj = *(const int4*)&tokens[(b << 8) + m0];
    const float* gr = &grow_lds[w * K_];
    const float* br = &brow_lds[w * K_];

    float s[4];
    s[0] = fmaf(gr[tj.x], fix_nonfinite(dv.x), br[tj.x]);
    s[1] = fmaf(gr[tj.y], fix_nonfinite(dv.y), br[tj.y]);
    s[2] = fmaf(gr[tj.z], fix_nonfinite(dv.z), br[tj.z]);
    s[3] = fmaf(gr[tj.w], fix_nonfinite(dv.w), br[tj.w]);

    int   i0[4];
    float fr[4];
    #pragma unroll
    for (int c = 0; c < 4; c++) {
        float tpos = (s[c] - smin) * invd;
        tpos = fminf(fmaxf(tpos, 0.0f), (float)(G_ - 1));
        int i = (int)tpos;
        if (i > G_ - 2) i = G_ - 2;
        i0[c] = i;
        fr[c] = tpos - (float)i;
    }

    // out[b][h][n][m0..m0+3]; base = b*H*N*N + n*N + m0
    size_t base = ((size_t)b << 20) | (uint32_t)(e0 & 0xFFFF);

    #pragma unroll
    for (int hq = 0; hq < 4; hq++) {       // h-quad: h = 4*hq .. 4*hq+3
        float4 P[4];
        #pragma unroll
        for (int c = 0; c < 4; c++) {
            float4 A  = tab[i0[c] * 4 + hq];
            float4 Bv = tab[i0[c] * 4 + 4 + hq];
            P[c].x = fmaf(fr[c], Bv.x - A.x, A.x);
            P[c].y = fmaf(fr[c], Bv.y - A.y, A.y);
            P[c].z = fmaf(fr[c], Bv.z - A.z, A.z);
            P[c].w = fmaf(fr[c], Bv.w - A.w, A.w);
        }
        float4 o0 = make_float4(P[0].x, P[1].x, P[2].x, P[3].x);
        float4 o1 = make_float4(P[0].y, P[1].y, P[2].y, P[3].y);
        float4 o2 = make_float4(P[0].z, P[1].z, P[2].z, P[3].z);
        float4 o3 = make_float4(P[0].w, P[1].w, P[2].w, P[3].w);
        *(float4*)&out[base + (size_t)(hq * 4 + 0) * (N_ * N_)] = o0;
        *(float4*)&out[base + (size_t)(hq * 4 + 1) * (N_ * N_)] = o1;
        *(float4*)&out[base + (size_t)(hq * 4 + 2) * (N_ * N_)] = o2;
        *(float4*)&out[base + (size_t)(hq * 4 + 3) * (N_ * N_)] = o3;
    }
}

extern "C" void kernel_launch(void* const* d_in, const int* in_sizes, int n_in,
                              void* d_out, int out_size, void* d_ws, size_t ws_size,
                              hipStream_t stream) {
    const float* d_mat     = (const float*)d_in[0];
    const int*   tokens    = (const int*)  d_in[1];
    const float* mu        = (const float*)d_in[2];
    const float* log_sigma = (const float*)d_in[3];
    const float* W1        = (const float*)d_in[4];
    const float* b1        = (const float*)d_in[5];
    const float* W2        = (const float*)d_in[6];
    const float* b2        = (const float*)d_in[7];
    const float* gamma_t   = (const float*)d_in[8];
    const float* beta_t    = (const float*)d_in[9];
    float* out = (float*)d_out;

    float*    mmf   = (float*)d_ws;                     // [smin, smax]
    uint32_t* pmin  = (uint32_t*)d_ws + 64;             // 256 partial mins (enc)
    uint32_t* pmax  = (uint32_t*)d_ws + 64 + 256;       // 256 partial maxs (enc)
    float*    table = (float*)d_ws + 1024;              // G_*H_ floats (64 KB), 16B-aligned

    k_partial<<<256, 256, 0, stream>>>((const float4*)d_mat, tokens, gamma_t, beta_t,
                                       pmin, pmax);
    k_table<<<G_, 128, 0, stream>>>(pmin, pmax, mu, log_sigma, W1, b1, W2, b2,
                                    table, mmf);
    k_main<<<512, 512, 0, stream>>>((const float4*)d_mat, tokens, gamma_t, beta_t,
                                    mmf, (const float4*)table, out);
}